// Round 6
// baseline (844.820 us; speedup 1.0000x reference)
//
#include <hip/hip_runtime.h>
#include <hip/hip_bf16.h>

#define D 128
#define EPS 1e-5f

// ---------- fused: edge count (atomics) + input-x row norms ----------
__global__ __launch_bounds__(256) void k_pre(
    const int* __restrict__ row, int* __restrict__ cnt, int E,
    const float* __restrict__ h, float* __restrict__ nrm, int N, int cB) {
  if ((int)blockIdx.x < cB) {
    int e = blockIdx.x * 256 + threadIdx.x;
    if (e < E) atomicAdd(&cnt[row[e]], 1);
  } else {
    int i = (blockIdx.x - cB) * 8 + (threadIdx.x >> 5);
    int sub = threadIdx.x & 31;
    if (i >= N) return;
    float4 a = ((const float4*)(h + (size_t)i * D))[sub];
    float v = a.x * a.x + a.y * a.y + a.z * a.z + a.w * a.w;
    for (int off = 16; off > 0; off >>= 1) v += __shfl_down(v, off, 32);
    if (sub == 0) nrm[i] = sqrtf(v);
  }
}

// ---------- two-level scan: bsum -> bscan -> apply ----------
// each block sums 1024 counts (cnt[i] for i>=N reads zeroed 'cur' region)
__global__ __launch_bounds__(256) void k_bsum(const int* __restrict__ cnt,
                                              int* __restrict__ bsum) {
  int t = threadIdx.x;
  int base = blockIdx.x * 1024 + t * 4;
  int4 c4 = ((const int4*)(cnt + base))[0];
  int s = c4.x + c4.y + c4.z + c4.w;
  for (int off = 32; off > 0; off >>= 1) s += __shfl_down(s, off);
  __shared__ int sh[4];
  if ((t & 63) == 0) sh[t >> 6] = s;
  __syncthreads();
  if (t == 0) bsum[blockIdx.x] = sh[0] + sh[1] + sh[2] + sh[3];
}

// single small block: exclusive scan of nb block sums; also writes rptr[N]=E
__global__ __launch_bounds__(256) void k_bscan(const int* __restrict__ bsum,
                                               int* __restrict__ boff, int nb,
                                               int* __restrict__ rptr, int N, int E) {
  __shared__ int sh[256];
  int t = threadIdx.x;
  int v = (t < nb) ? bsum[t] : 0;
  sh[t] = v;
  __syncthreads();
  for (int off = 1; off < 256; off <<= 1) {
    int u = (t >= off) ? sh[t - off] : 0;
    __syncthreads();
    sh[t] += u;
    __syncthreads();
  }
  if (t < nb) boff[t] = sh[t] - v;     // exclusive
  if (t == 0) rptr[N] = E;
}

// each block exclusive-scans its 1024 counts with block offset -> rptr
__global__ __launch_bounds__(256) void k_apply(const int* __restrict__ cnt,
                                               const int* __restrict__ boff,
                                               int* __restrict__ rptr, int N) {
  __shared__ int sh[256];
  int t = threadIdx.x;
  int base = blockIdx.x * 1024 + t * 4;
  int4 c4 = ((const int4*)(cnt + base))[0];
  int e0 = 0, e1 = c4.x, e2 = c4.x + c4.y, e3 = c4.x + c4.y + c4.z;
  int tot = e3 + c4.w;
  sh[t] = tot;
  __syncthreads();
  for (int off = 1; off < 256; off <<= 1) {
    int u = (t >= off) ? sh[t - off] : 0;
    __syncthreads();
    sh[t] += u;
    __syncthreads();
  }
  int o = sh[t] - tot + boff[blockIdx.x];
  if (base + 0 < N) rptr[base + 0] = o + e0;
  if (base + 1 < N) rptr[base + 1] = o + e1;
  if (base + 2 < N) rptr[base + 2] = o + e2;
  if (base + 3 < N) rptr[base + 3] = o + e3;
}

__global__ __launch_bounds__(256) void k_scatter(
    const int* __restrict__ row, const int* __restrict__ col,
    const int* __restrict__ rptr, int* __restrict__ cur,
    int* __restrict__ rowS, int* __restrict__ colS, int E) {
  int e = blockIdx.x * 256 + threadIdx.x;
  if (e < E) {
    int r = row[e];
    int p = rptr[r] + atomicAdd(&cur[r], 1);
    rowS[p] = r;
    colS[p] = col[e];
  }
}

__global__ __launch_bounds__(256) void k_rev(const int* __restrict__ rowS,
                                             const int* __restrict__ colS,
                                             const int* __restrict__ rptr,
                                             int* __restrict__ rev, int E) {
  int p = blockIdx.x * 256 + threadIdx.x;
  if (p >= E) return;
  int r = rowS[p], c = colS[p];
  int q1 = rptr[c + 1];
  int rv = -1;
  for (int q = rptr[c]; q < q1; ++q)
    if (colS[q] == r) { rv = q; break; }
  rev[p] = rv;
}

// ---------- fused sim (node-centric, 8 gathers in flight) + GEMM ----------
// blocks [0,nG): s = h @ W, BM=64, 256 thr, 4x8/thread, Ws-only LDS (32KB).
// blocks [nG,..): per-node cosine sim + fused row-sum.
__global__ __launch_bounds__(256) void k_simgemm(
    const float* __restrict__ h, const float* __restrict__ nrm,
    const int* __restrict__ rptr, const int* __restrict__ colS,
    float* __restrict__ simS, float* __restrict__ rsE,
    const float* __restrict__ W, float* __restrict__ S, int N, int nG) {
  __shared__ float Ws[64 * D];         // 32 KB (one K-phase of W)
  int t = threadIdx.x;
  if ((int)blockIdx.x < nG) {
    int i0 = blockIdx.x * 64;
    int tx = t & 15, ty = t >> 4;      // rows 4ty..4ty+3, cols 4tx & 64+4tx
    int gi[4];
    bool vld[4];
#pragma unroll
    for (int r = 0; r < 4; ++r) {
      gi[r] = i0 + ty * 4 + r;
      vld[r] = gi[r] < N;
    }
    float acc[4][8] = {};
    for (int ph = 0; ph < 2; ++ph) {
      __syncthreads();
      for (int ch = 0; ch < 8; ++ch) {
        int q = t + 256 * ch;          // [0,2048) float4 slots
        ((float4*)Ws)[q] = ((const float4*)(W + (size_t)ph * 64 * D))[q];
      }
      __syncthreads();
      for (int kk = 0; kk < 16; ++kk) {
        float4 a4[4];
#pragma unroll
        for (int r = 0; r < 4; ++r)
          a4[r] = vld[r] ? ((const float4*)(h + (size_t)gi[r] * D))[ph * 16 + kk]
                         : make_float4(0.f, 0.f, 0.f, 0.f);
        float4 b0[4], b1[4];
#pragma unroll
        for (int k = 0; k < 4; ++k) {
          b0[k] = ((const float4*)(Ws + (kk * 4 + k) * D))[tx];
          b1[k] = ((const float4*)(Ws + (kk * 4 + k) * D))[16 + tx];
        }
#pragma unroll
        for (int r = 0; r < 4; ++r) {
          float4 a = a4[r];
#pragma unroll
          for (int c = 0; c < 4; ++c) {
            acc[r][c] += a.x * (&b0[0].x)[c] + a.y * (&b0[1].x)[c] +
                         a.z * (&b0[2].x)[c] + a.w * (&b0[3].x)[c];
            acc[r][4 + c] += a.x * (&b1[0].x)[c] + a.y * (&b1[1].x)[c] +
                             a.z * (&b1[2].x)[c] + a.w * (&b1[3].x)[c];
          }
        }
      }
    }
#pragma unroll
    for (int r = 0; r < 4; ++r) {
      if (vld[r]) {
        ((float4*)(S + (size_t)gi[r] * D))[tx] =
            make_float4(acc[r][0], acc[r][1], acc[r][2], acc[r][3]);
        ((float4*)(S + (size_t)gi[r] * D))[16 + tx] =
            make_float4(acc[r][4], acc[r][5], acc[r][6], acc[r][7]);
      }
    }
  } else {
    int i = (blockIdx.x - nG) * 4 + (t >> 6);
    if (i >= N) return;
    int lane = t & 63;
    int sub = lane & 31;
    int half = lane >> 5;
    int p0 = rptr[i], p1 = rptr[i + 1];
    float4 ai = ((const float4*)(h + (size_t)i * D))[sub];
    float ni = nrm[i];
    float rs = 0.f;
    for (int base = p0; base < p1; base += 8) {
      int p[4], c[4];
      bool val[4];
      float4 b[4];
#pragma unroll
      for (int k = 0; k < 4; ++k) {
        p[k] = base + 2 * k + half;
        val[k] = p[k] < p1;
        c[k] = val[k] ? colS[p[k]] : i;
      }
#pragma unroll
      for (int k = 0; k < 4; ++k)
        b[k] = ((const float4*)(h + (size_t)c[k] * D))[sub];
#pragma unroll
      for (int k = 0; k < 4; ++k) {
        float v = ai.x * b[k].x + ai.y * b[k].y + ai.z * b[k].z + ai.w * b[k].w;
        for (int off = 16; off > 0; off >>= 1) v += __shfl_down(v, off, 32);
        if (sub == 0 && val[k]) {
          float sm = v / (ni * nrm[c[k]]);
          sm = (sm < 0.1f) ? 0.0f : sm;
          simS[p[k]] = sm;
          rs += sm;
        }
      }
    }
    rs += __shfl_xor(rs, 32);
    if (lane == 0) rsE[i] = (rs > 0.f) ? rs : 1.f;
  }
}

// ---------- fused: drop-mask + aggregate + self + bias + LN/ReLU or log_softmax
template <int MODE>
__global__ __launch_bounds__(256) void k_combine(
    const float* __restrict__ s, const float* __restrict__ simS,
    const float* __restrict__ rsE, const int* __restrict__ rev,
    const int* __restrict__ rptr, const int* __restrict__ colS,
    const float* __restrict__ bias, const float* __restrict__ g,
    const float* __restrict__ be, const float* __restrict__ dWp,
    const float* __restrict__ dbp, float* __restrict__ outF,
    float* __restrict__ nrmOut, int N) {
  int i = blockIdx.x;
  int t = threadIdx.x;
  int grp = t >> 5, sub = t & 31;
  __shared__ float sw[256];
  __shared__ int scl[256];
  __shared__ float accL[8 * 128];
  __shared__ int scnt;
  float w0 = dWp[0], w1 = dWp[1], bd = dbp[0];
  int p0 = rptr[i], p1 = rptr[i + 1];
  float ri = rsE[i];
  float4 acc = make_float4(0.f, 0.f, 0.f, 0.f);
  int deg = 0;
  for (int base = p0; base < p1; base += 256) {
    int m = min(256, p1 - base);
    if (t == 0) scnt = 0;
    __syncthreads();
    if (t < m) {
      int p = base + t;
      float sm = simS[p];
      if (sm != 0.f) {
        float a = sm / ri;
        int rv = rev[p];
        int c = colS[p];
        float ar = (rv >= 0) ? simS[rv] / rsE[c] : 0.f;
        float x = a * w0 + ar * w1 + bd;
        float sc = (x >= 0.f) ? 1.f / (1.f + expf(-x)) : expf(x) / (1.f + expf(x));
        if (sc > 0.5f) {
          int sl = atomicAdd(&scnt, 1);
          sw[sl] = expf(a);
          scl[sl] = c;
        }
      }
    }
    __syncthreads();
    int K = scnt;
    deg += K;
    for (int j = grp; j < K; j += 8) {
      int c = scl[j];
      float w = sw[j];
      float4 sv = ((const float4*)(s + (size_t)c * D))[sub];
      acc.x += w * sv.x; acc.y += w * sv.y;
      acc.z += w * sv.z; acc.w += w * sv.w;
    }
    __syncthreads();                   // sw/scl reused next chunk
  }
  ((float4*)accL)[grp * 32 + sub] = acc;
  __syncthreads();
  if (t < 32) {
    float4 tot = make_float4(0.f, 0.f, 0.f, 0.f);
#pragma unroll
    for (int gq = 0; gq < 8; ++gq) {
      float4 a4 = ((const float4*)accL)[gq * 32 + t];
      tot.x += a4.x; tot.y += a4.y; tot.z += a4.z; tot.w += a4.w;
    }
    float wd = expf(1.0f / (float)(deg + 1));
    float4 sv = ((const float4*)(s + (size_t)i * D))[t];
    float4 bb = ((const float4*)bias)[t];
    float4 v = make_float4(tot.x + wd * sv.x + bb.x, tot.y + wd * sv.y + bb.y,
                           tot.z + wd * sv.z + bb.z, tot.w + wd * sv.w + bb.w);
    if (MODE == 0) {
      float sm = v.x + v.y + v.z + v.w;
      for (int off = 16; off > 0; off >>= 1) sm += __shfl_down(sm, off, 32);
      float mu = __shfl(sm, 0, 32) * (1.f / 128.f);
      float4 dv = make_float4(v.x - mu, v.y - mu, v.z - mu, v.w - mu);
      float q = dv.x * dv.x + dv.y * dv.y + dv.z * dv.z + dv.w * dv.w;
      for (int off = 16; off > 0; off >>= 1) q += __shfl_down(q, off, 32);
      float var = __shfl(q, 0, 32) * (1.f / 128.f);
      float rstd = rsqrtf(var + EPS);
      float4 gg = ((const float4*)g)[t];
      float4 eb = ((const float4*)be)[t];
      float4 y = make_float4(fmaxf(dv.x * rstd * gg.x + eb.x, 0.f),
                             fmaxf(dv.y * rstd * gg.y + eb.y, 0.f),
                             fmaxf(dv.z * rstd * gg.z + eb.z, 0.f),
                             fmaxf(dv.w * rstd * gg.w + eb.w, 0.f));
      ((float4*)(outF + (size_t)i * D))[t] = y;
      float q2 = y.x * y.x + y.y * y.y + y.z * y.z + y.w * y.w;
      for (int off = 16; off > 0; off >>= 1) q2 += __shfl_down(q2, off, 32);
      if (t == 0) nrmOut[i] = sqrtf(q2);
    } else {
      float mx = fmaxf(fmaxf(v.x, v.y), fmaxf(v.z, v.w));
      for (int off = 16; off > 0; off >>= 1) mx = fmaxf(mx, __shfl_down(mx, off, 32));
      float m = __shfl(mx, 0, 32);
      float es = expf(v.x - m) + expf(v.y - m) + expf(v.z - m) + expf(v.w - m);
      for (int off = 16; off > 0; off >>= 1) es += __shfl_down(es, off, 32);
      float l = logf(__shfl(es, 0, 32)) + m;
      ((float4*)(outF + (size_t)i * D))[t] =
          make_float4(v.x - l, v.y - l, v.z - l, v.w - l);
    }
  }
}

extern "C" void kernel_launch(void* const* d_in, const int* in_sizes, int n_in,
                              void* d_out, int out_size, void* d_ws, size_t ws_size,
                              hipStream_t stream) {
  const float* x   = (const float*)d_in[0];
  const float* W0  = (const float*)d_in[1];
  const float* b0  = (const float*)d_in[2];
  const float* W1  = (const float*)d_in[3];
  const float* b1  = (const float*)d_in[4];
  const float* g1  = (const float*)d_in[5];
  const float* be1 = (const float*)d_in[6];
  const float* g2  = (const float*)d_in[7];
  const float* be2 = (const float*)d_in[8];
  const float* dW  = (const float*)d_in[9];
  const float* db  = (const float*)d_in[10];
  const int* row   = (const int*)d_in[11];
  const int* col   = (const int*)d_in[12];
  int N = in_sizes[0] / D;
  int E = in_sizes[11];
  float* out = (float*)d_out;

  float* base = (float*)d_ws;
  size_t off = 0;
  auto alloc = [&](size_t elems) {
    float* p = base + off;
    off += (elems + 3) & ~(size_t)3;
    return p;
  };
  size_t N128 = (size_t)N * D;
  int nb = (N + 1023) / 1024;          // scan blocks (1024 counts each)
  int NpadS = nb * 1024;               // cnt region must cover int4 tail reads
  float* hA   = alloc(N128);
  float* hB   = alloc(N128);
  float* s    = alloc(N128);
  int*   rowS = (int*)alloc(E);
  int*   colS = (int*)alloc(E);
  int*   rev  = (int*)alloc(E);
  float* simS = alloc(E);
  int*   cc   = (int*)alloc((size_t)2 * NpadS);  // cnt | cur (zeroed together)
  int*   cnt  = cc;
  int*   cur  = cc + NpadS;
  int*   rptr = (int*)alloc(N + 1);
  float* rsE  = alloc(N);
  float* nrm  = alloc(N);
  int*   bsum = (int*)alloc(nb);
  int*   boff = (int*)alloc(nb);
  (void)ws_size; (void)n_in; (void)out_size;

  int cB = (E + 255) / 256;
  int nB = (N + 7) / 8;
  int nG = (N + 63) / 64;
  int nS = (N + 3) / 4;

  hipMemsetAsync(cc, 0, (size_t)2 * NpadS * sizeof(int), stream);
  k_pre<<<cB + nB, 256, 0, stream>>>(row, cnt, E, x, nrm, N, cB);
  k_bsum<<<nb, 256, 0, stream>>>(cnt, bsum);
  k_bscan<<<1, 256, 0, stream>>>(bsum, boff, nb, rptr, N, E);
  k_apply<<<nb, 256, 0, stream>>>(cnt, boff, rptr, N);
  k_scatter<<<cB, 256, 0, stream>>>(row, col, rptr, cur, rowS, colS, E);
  k_rev<<<cB, 256, 0, stream>>>(rowS, colS, rptr, rev, E);

  auto layer = [&](const float* hin, float* hout, const float* Wf,
                   const float* bf, const float* gf, const float* bef,
                   float* nrmOut, int mode) {
    k_simgemm<<<nG + nS, 256, 0, stream>>>(hin, nrm, rptr, colS, simS, rsE, Wf,
                                           s, N, nG);
    if (mode == 0)
      k_combine<0><<<N, 256, 0, stream>>>(s, simS, rsE, rev, rptr, colS, bf, gf,
                                          bef, dW, db, hout, nrmOut, N);
    else
      k_combine<1><<<N, 256, 0, stream>>>(s, simS, rsE, rev, rptr, colS, bf, gf,
                                          bef, dW, db, hout, nullptr, N);
  };
  // layer 0: x -> hA (W0, b0, ln1); writes nrm of hA
  layer(x, hA, W0, b0, g1, be1, nrm, 0);
  // layer 1: hA -> hB (W1, b1, ln2); writes nrm of hB
  layer(hA, hB, W1, b1, g2, be2, nrm, 0);
  // final: hB -> out (W1, b1, log_softmax)  [source bug reuses convs[-2]]
  layer(hB, out, W1, b1, nullptr, nullptr, nullptr, 1);
}

// Round 7
// 801.657 us; speedup vs baseline: 1.0538x; 1.0538x over previous
//
#include <hip/hip_runtime.h>
#include <hip/hip_bf16.h>

#define D 128
#define EPS 1e-5f

// ---------- fused: edge count (atomics) + input-x row norms ----------
__global__ __launch_bounds__(256) void k_pre(
    const int* __restrict__ row, int* __restrict__ cnt, int E,
    const float* __restrict__ h, float* __restrict__ nrm, int N, int cB) {
  if ((int)blockIdx.x < cB) {
    int e = blockIdx.x * 256 + threadIdx.x;
    if (e < E) atomicAdd(&cnt[row[e]], 1);
  } else {
    int i = (blockIdx.x - cB) * 8 + (threadIdx.x >> 5);
    int sub = threadIdx.x & 31;
    if (i >= N) return;
    float4 a = ((const float4*)(h + (size_t)i * D))[sub];
    float v = a.x * a.x + a.y * a.y + a.z * a.z + a.w * a.w;
    for (int off = 16; off > 0; off >>= 1) v += __shfl_down(v, off, 32);
    if (sub == 0) nrm[i] = sqrtf(v);
  }
}

// ---------- two-level scan: bsum -> bscan -> apply ----------
__global__ __launch_bounds__(256) void k_bsum(const int* __restrict__ cnt,
                                              int* __restrict__ bsum) {
  int t = threadIdx.x;
  int base = blockIdx.x * 1024 + t * 4;
  int4 c4 = ((const int4*)(cnt + base))[0];
  int s = c4.x + c4.y + c4.z + c4.w;
  for (int off = 32; off > 0; off >>= 1) s += __shfl_down(s, off);
  __shared__ int sh[4];
  if ((t & 63) == 0) sh[t >> 6] = s;
  __syncthreads();
  if (t == 0) bsum[blockIdx.x] = sh[0] + sh[1] + sh[2] + sh[3];
}

__global__ __launch_bounds__(256) void k_bscan(const int* __restrict__ bsum,
                                               int* __restrict__ boff, int nb,
                                               int* __restrict__ rptr, int N, int E) {
  __shared__ int sh[256];
  int t = threadIdx.x;
  int v = (t < nb) ? bsum[t] : 0;
  sh[t] = v;
  __syncthreads();
  for (int off = 1; off < 256; off <<= 1) {
    int u = (t >= off) ? sh[t - off] : 0;
    __syncthreads();
    sh[t] += u;
    __syncthreads();
  }
  if (t < nb) boff[t] = sh[t] - v;     // exclusive
  if (t == 0) rptr[N] = E;
}

__global__ __launch_bounds__(256) void k_apply(const int* __restrict__ cnt,
                                               const int* __restrict__ boff,
                                               int* __restrict__ rptr, int N) {
  __shared__ int sh[256];
  int t = threadIdx.x;
  int base = blockIdx.x * 1024 + t * 4;
  int4 c4 = ((const int4*)(cnt + base))[0];
  int e1 = c4.x, e2 = c4.x + c4.y, e3 = c4.x + c4.y + c4.z;
  int tot = e3 + c4.w;
  sh[t] = tot;
  __syncthreads();
  for (int off = 1; off < 256; off <<= 1) {
    int u = (t >= off) ? sh[t - off] : 0;
    __syncthreads();
    sh[t] += u;
    __syncthreads();
  }
  int o = sh[t] - tot + boff[blockIdx.x];
  if (base + 0 < N) rptr[base + 0] = o;
  if (base + 1 < N) rptr[base + 1] = o + e1;
  if (base + 2 < N) rptr[base + 2] = o + e2;
  if (base + 3 < N) rptr[base + 3] = o + e3;
}

__global__ __launch_bounds__(256) void k_scatter(
    const int* __restrict__ row, const int* __restrict__ col,
    const int* __restrict__ rptr, int* __restrict__ cur,
    int* __restrict__ rowS, int* __restrict__ colS, int E) {
  int e = blockIdx.x * 256 + threadIdx.x;
  if (e < E) {
    int r = row[e];
    int p = rptr[r] + atomicAdd(&cur[r], 1);
    rowS[p] = r;
    colS[p] = col[e];
  }
}

__global__ __launch_bounds__(256) void k_rev(const int* __restrict__ rowS,
                                             const int* __restrict__ colS,
                                             const int* __restrict__ rptr,
                                             int* __restrict__ rev, int E) {
  int p = blockIdx.x * 256 + threadIdx.x;
  if (p >= E) return;
  int r = rowS[p], c = colS[p];
  int q1 = rptr[c + 1];
  int rv = -1;
  for (int q = rptr[c]; q < q1; ++q)
    if (colS[q] == r) { rv = q; break; }
  rev[p] = rv;
}

// ---------- node-centric sim + fused row-sum, 16 neighbors in flight ----------
__global__ __launch_bounds__(256) void k_sim(
    const float* __restrict__ h, const float* __restrict__ nrm,
    const int* __restrict__ rptr, const int* __restrict__ colS,
    float* __restrict__ simS, float* __restrict__ rsE, int N) {
  int i = blockIdx.x * 4 + (threadIdx.x >> 6);
  if (i >= N) return;
  int lane = threadIdx.x & 63;
  int sub = lane & 31;
  int half = lane >> 5;
  int p0 = rptr[i], p1 = rptr[i + 1];
  float4 ai = ((const float4*)(h + (size_t)i * D))[sub];
  float ni = nrm[i];
  float rs = 0.f;
  for (int base = p0; base < p1; base += 16) {
    int p[8], c[8];
    bool val[8];
    float4 b[8];
#pragma unroll
    for (int k = 0; k < 8; ++k) {
      p[k] = base + 2 * k + half;
      val[k] = p[k] < p1;
      c[k] = val[k] ? colS[p[k]] : i;
    }
#pragma unroll
    for (int k = 0; k < 8; ++k)
      b[k] = ((const float4*)(h + (size_t)c[k] * D))[sub];
#pragma unroll
    for (int k = 0; k < 8; ++k) {
      float v = ai.x * b[k].x + ai.y * b[k].y + ai.z * b[k].z + ai.w * b[k].w;
      for (int off = 16; off > 0; off >>= 1) v += __shfl_down(v, off, 32);
      if (sub == 0 && val[k]) {
        float sm = v / (ni * nrm[c[k]]);
        sm = (sm < 0.1f) ? 0.0f : sm;
        simS[p[k]] = sm;
        rs += sm;
      }
    }
  }
  rs += __shfl_xor(rs, 32);
  if (lane == 0) rsE[i] = (rs > 0.f) ? rs : 1.f;
}

// ---------- s = h @ W (f32, BM=64, 256 thr, 4x8/thread, Ws-only LDS) ----------
__global__ __launch_bounds__(256) void k_gemm(const float* __restrict__ h,
                                              const float* __restrict__ W,
                                              float* __restrict__ S, int N) {
  __shared__ float Ws[64 * D];         // 32 KB (one K-phase of W)
  int t = threadIdx.x;
  int i0 = blockIdx.x * 64;
  int tx = t & 15, ty = t >> 4;        // rows 4ty..4ty+3, cols 4tx & 64+4tx
  int gi[4];
  bool vld[4];
#pragma unroll
  for (int r = 0; r < 4; ++r) {
    gi[r] = i0 + ty * 4 + r;
    vld[r] = gi[r] < N;
  }
  float acc[4][8] = {};
  for (int ph = 0; ph < 2; ++ph) {
    __syncthreads();
    for (int ch = 0; ch < 8; ++ch) {
      int q = t + 256 * ch;            // [0,2048) float4 slots
      ((float4*)Ws)[q] = ((const float4*)(W + (size_t)ph * 64 * D))[q];
    }
    __syncthreads();
    for (int kk = 0; kk < 16; ++kk) {
      float4 a4[4];
#pragma unroll
      for (int r = 0; r < 4; ++r)
        a4[r] = vld[r] ? ((const float4*)(h + (size_t)gi[r] * D))[ph * 16 + kk]
                       : make_float4(0.f, 0.f, 0.f, 0.f);
      float4 b0[4], b1[4];
#pragma unroll
      for (int k = 0; k < 4; ++k) {
        b0[k] = ((const float4*)(Ws + (kk * 4 + k) * D))[tx];
        b1[k] = ((const float4*)(Ws + (kk * 4 + k) * D))[16 + tx];
      }
#pragma unroll
      for (int r = 0; r < 4; ++r) {
        float4 a = a4[r];
#pragma unroll
        for (int c = 0; c < 4; ++c) {
          acc[r][c] += a.x * (&b0[0].x)[c] + a.y * (&b0[1].x)[c] +
                       a.z * (&b0[2].x)[c] + a.w * (&b0[3].x)[c];
          acc[r][4 + c] += a.x * (&b1[0].x)[c] + a.y * (&b1[1].x)[c] +
                           a.z * (&b1[2].x)[c] + a.w * (&b1[3].x)[c];
        }
      }
    }
  }
#pragma unroll
  for (int r = 0; r < 4; ++r) {
    if (vld[r]) {
      ((float4*)(S + (size_t)gi[r] * D))[tx] =
          make_float4(acc[r][0], acc[r][1], acc[r][2], acc[r][3]);
      ((float4*)(S + (size_t)gi[r] * D))[16 + tx] =
          make_float4(acc[r][4], acc[r][5], acc[r][6], acc[r][7]);
    }
  }
}

// ---------- fused: drop-mask + aggregate + self + bias + LN/ReLU or log_softmax
template <int MODE>
__global__ __launch_bounds__(256) void k_combine(
    const float* __restrict__ s, const float* __restrict__ simS,
    const float* __restrict__ rsE, const int* __restrict__ rev,
    const int* __restrict__ rptr, const int* __restrict__ colS,
    const float* __restrict__ bias, const float* __restrict__ g,
    const float* __restrict__ be, const float* __restrict__ dWp,
    const float* __restrict__ dbp, float* __restrict__ outF,
    float* __restrict__ nrmOut, int N) {
  int i = blockIdx.x;
  int t = threadIdx.x;
  int grp = t >> 5, sub = t & 31;
  __shared__ float sw[256];
  __shared__ int scl[256];
  __shared__ float accL[8 * 128];
  __shared__ int scnt;
  float w0 = dWp[0], w1 = dWp[1], bd = dbp[0];
  int p0 = rptr[i], p1 = rptr[i + 1];
  float ri = rsE[i];
  float4 acc = make_float4(0.f, 0.f, 0.f, 0.f);
  int deg = 0;
  for (int base = p0; base < p1; base += 256) {
    int m = min(256, p1 - base);
    if (t == 0) scnt = 0;
    __syncthreads();
    if (t < m) {
      int p = base + t;
      float sm = simS[p];
      if (sm != 0.f) {
        float a = sm / ri;
        int rv = rev[p];
        int c = colS[p];
        float ar = (rv >= 0) ? simS[rv] / rsE[c] : 0.f;
        float x = a * w0 + ar * w1 + bd;
        float sc = (x >= 0.f) ? 1.f / (1.f + expf(-x)) : expf(x) / (1.f + expf(x));
        if (sc > 0.5f) {
          int sl = atomicAdd(&scnt, 1);
          sw[sl] = expf(a);
          scl[sl] = c;
        }
      }
    }
    __syncthreads();
    int K = scnt;
    deg += K;
    for (int j = grp; j < K; j += 8) {
      int c = scl[j];
      float w = sw[j];
      float4 sv = ((const float4*)(s + (size_t)c * D))[sub];
      acc.x += w * sv.x; acc.y += w * sv.y;
      acc.z += w * sv.z; acc.w += w * sv.w;
    }
    __syncthreads();                   // sw/scl reused next chunk
  }
  ((float4*)accL)[grp * 32 + sub] = acc;
  __syncthreads();
  if (t < 32) {
    float4 tot = make_float4(0.f, 0.f, 0.f, 0.f);
#pragma unroll
    for (int gq = 0; gq < 8; ++gq) {
      float4 a4 = ((const float4*)accL)[gq * 32 + t];
      tot.x += a4.x; tot.y += a4.y; tot.z += a4.z; tot.w += a4.w;
    }
    float wd = expf(1.0f / (float)(deg + 1));
    float4 sv = ((const float4*)(s + (size_t)i * D))[t];
    float4 bb = ((const float4*)bias)[t];
    float4 v = make_float4(tot.x + wd * sv.x + bb.x, tot.y + wd * sv.y + bb.y,
                           tot.z + wd * sv.z + bb.z, tot.w + wd * sv.w + bb.w);
    if (MODE == 0) {
      float sm = v.x + v.y + v.z + v.w;
      for (int off = 16; off > 0; off >>= 1) sm += __shfl_down(sm, off, 32);
      float mu = __shfl(sm, 0, 32) * (1.f / 128.f);
      float4 dv = make_float4(v.x - mu, v.y - mu, v.z - mu, v.w - mu);
      float q = dv.x * dv.x + dv.y * dv.y + dv.z * dv.z + dv.w * dv.w;
      for (int off = 16; off > 0; off >>= 1) q += __shfl_down(q, off, 32);
      float var = __shfl(q, 0, 32) * (1.f / 128.f);
      float rstd = rsqrtf(var + EPS);
      float4 gg = ((const float4*)g)[t];
      float4 eb = ((const float4*)be)[t];
      float4 y = make_float4(fmaxf(dv.x * rstd * gg.x + eb.x, 0.f),
                             fmaxf(dv.y * rstd * gg.y + eb.y, 0.f),
                             fmaxf(dv.z * rstd * gg.z + eb.z, 0.f),
                             fmaxf(dv.w * rstd * gg.w + eb.w, 0.f));
      ((float4*)(outF + (size_t)i * D))[t] = y;
      float q2 = y.x * y.x + y.y * y.y + y.z * y.z + y.w * y.w;
      for (int off = 16; off > 0; off >>= 1) q2 += __shfl_down(q2, off, 32);
      if (t == 0) nrmOut[i] = sqrtf(q2);
    } else {
      float mx = fmaxf(fmaxf(v.x, v.y), fmaxf(v.z, v.w));
      for (int off = 16; off > 0; off >>= 1) mx = fmaxf(mx, __shfl_down(mx, off, 32));
      float m = __shfl(mx, 0, 32);
      float es = expf(v.x - m) + expf(v.y - m) + expf(v.z - m) + expf(v.w - m);
      for (int off = 16; off > 0; off >>= 1) es += __shfl_down(es, off, 32);
      float l = logf(__shfl(es, 0, 32)) + m;
      ((float4*)(outF + (size_t)i * D))[t] =
          make_float4(v.x - l, v.y - l, v.z - l, v.w - l);
    }
  }
}

extern "C" void kernel_launch(void* const* d_in, const int* in_sizes, int n_in,
                              void* d_out, int out_size, void* d_ws, size_t ws_size,
                              hipStream_t stream) {
  const float* x   = (const float*)d_in[0];
  const float* W0  = (const float*)d_in[1];
  const float* b0  = (const float*)d_in[2];
  const float* W1  = (const float*)d_in[3];
  const float* b1  = (const float*)d_in[4];
  const float* g1  = (const float*)d_in[5];
  const float* be1 = (const float*)d_in[6];
  const float* g2  = (const float*)d_in[7];
  const float* be2 = (const float*)d_in[8];
  const float* dW  = (const float*)d_in[9];
  const float* db  = (const float*)d_in[10];
  const int* row   = (const int*)d_in[11];
  const int* col   = (const int*)d_in[12];
  int N = in_sizes[0] / D;
  int E = in_sizes[11];
  float* out = (float*)d_out;

  float* base = (float*)d_ws;
  size_t off = 0;
  auto alloc = [&](size_t elems) {
    float* p = base + off;
    off += (elems + 3) & ~(size_t)3;
    return p;
  };
  size_t N128 = (size_t)N * D;
  int nb = (N + 1023) / 1024;          // scan blocks (1024 counts each)
  int NpadS = nb * 1024;               // cnt region covers int4 tail reads
  float* hA   = alloc(N128);
  float* hB   = alloc(N128);
  float* s    = alloc(N128);
  int*   rowS = (int*)alloc(E);
  int*   colS = (int*)alloc(E);
  int*   rev  = (int*)alloc(E);
  float* simS = alloc(E);
  int*   cc   = (int*)alloc((size_t)2 * NpadS);  // cnt | cur (zeroed together)
  int*   cnt  = cc;
  int*   cur  = cc + NpadS;
  int*   rptr = (int*)alloc(N + 1);
  float* rsE  = alloc(N);
  float* nrm  = alloc(N);
  int*   bsum = (int*)alloc(nb);
  int*   boff = (int*)alloc(nb);
  (void)ws_size; (void)n_in; (void)out_size;

  int cB = (E + 255) / 256;
  int nB = (N + 7) / 8;
  int nG = (N + 63) / 64;
  int nS = (N + 3) / 4;

  hipMemsetAsync(cc, 0, (size_t)2 * NpadS * sizeof(int), stream);
  k_pre<<<cB + nB, 256, 0, stream>>>(row, cnt, E, x, nrm, N, cB);
  k_bsum<<<nb, 256, 0, stream>>>(cnt, bsum);
  k_bscan<<<1, 256, 0, stream>>>(bsum, boff, nb, rptr, N, E);
  k_apply<<<nb, 256, 0, stream>>>(cnt, boff, rptr, N);
  k_scatter<<<cB, 256, 0, stream>>>(row, col, rptr, cur, rowS, colS, E);
  k_rev<<<cB, 256, 0, stream>>>(rowS, colS, rptr, rev, E);

  auto layer = [&](const float* hin, float* hout, const float* Wf,
                   const float* bf, const float* gf, const float* bef,
                   float* nrmOut, int mode) {
    k_sim<<<nS, 256, 0, stream>>>(hin, nrm, rptr, colS, simS, rsE, N);
    k_gemm<<<nG, 256, 0, stream>>>(hin, Wf, s, N);
    if (mode == 0)
      k_combine<0><<<N, 256, 0, stream>>>(s, simS, rsE, rev, rptr, colS, bf, gf,
                                          bef, dW, db, hout, nrmOut, N);
    else
      k_combine<1><<<N, 256, 0, stream>>>(s, simS, rsE, rev, rptr, colS, bf, gf,
                                          bef, dW, db, hout, nullptr, N);
  };
  // layer 0: x -> hA (W0, b0, ln1); writes nrm of hA
  layer(x, hA, W0, b0, g1, be1, nrm, 0);
  // layer 1: hA -> hB (W1, b1, ln2); writes nrm of hB
  layer(hA, hB, W1, b1, g2, be2, nrm, 0);
  // final: hB -> out (W1, b1, log_softmax)  [source bug reuses convs[-2]]
  layer(hB, out, W1, b1, nullptr, nullptr, nullptr, 1);
}